// Round 19
// baseline (147.701 us; speedup 1.0000x reference)
//
#include <hip/hip_runtime.h>
#include <math.h>

#define N_NODES 50000
#define N_EDGES 1600000
#define N_RELS 8
#define N_BASES 4
#define HD 64

#define NB_D 196                 // ceil(50000/256) blocks in d_table_kernel
#define NB_E 391                 // edge kernel: 391*256 threads * 4 quads = 400384 >= 400000
#define NTHR_E (NB_E * 256)      // 100096
#define NQUAD (N_EDGES / 4)      // 400000

typedef int      vint4   __attribute__((ext_vector_type(4)));
typedef float    vfloat4 __attribute__((ext_vector_type(4)));
typedef _Float16 half4v  __attribute__((ext_vector_type(4)));   // 8B: one (v,r) D entry
typedef _Float16 half8v  __attribute__((ext_vector_type(8)));   // 16B: two entries (store side)

// ws layout (floats):
//   partials    at PART_OFF   [0..NB_D+NB_E) = [0..587)
//   ticket(int) at TICKET_OFF [2048]
//   D           at D_OFF      v-major fp16: half4v index = v*8 + r
//                             (d0,d1,d2,0) per (v,r) -> 8B, 64B per node, 3.2 MB total
#define PART_OFF   0
#define TICKET_OFF 2048
#define D_OFF      4096

// ---------------------------------------------------------------------------
// Fused: per-block G build (in LDS) + D-table projection. Block 0 also resets
// the edge-kernel ticket (visible to the next dispatch by stream ordering).
__global__ __launch_bounds__(256) void d_table_kernel(
        const float* __restrict__ W_in,
        const float* __restrict__ b_in,
        const float* __restrict__ w_comp,
        const float* __restrict__ bases,
        const float* __restrict__ loop_w,
        const float* __restrict__ h_bias,
        const vfloat4* __restrict__ fcW4,
        const float2* __restrict__ feat,
        half8v* __restrict__ D16,        // index v*4 + j  (rel pair j)
        float* __restrict__ partD,
        int* __restrict__ ticket) {
    __shared__ float sA[N_BASES * 3 * HD];   // A[b][k][o]
    __shared__ float sG[27 * HD];            // G[j][o]
    const int tid = threadIdx.x;

    if (blockIdx.x == 0 && tid == 0) *ticket = 0;   // per-launch reset

    // ---- G build (identical math to the old prep_kernel, LDS-resident) ----
    {
        const int o = tid & 63;
        const int b = tid >> 6;              // 0..3
        float s0 = 0.f, s1 = 0.f, sb = 0.f;
        for (int i = 0; i < HD; i++) {
            float bv = bases[b * HD * HD + i * HD + o];
            s0 += W_in[i]      * bv;
            s1 += W_in[HD + i] * bv;
            sb += b_in[i]      * bv;
        }
        sA[(b * 3 + 0) * HD + o] = s0;
        sA[(b * 3 + 1) * HD + o] = s1;
        sA[(b * 3 + 2) * HD + o] = sb;
    }
    __syncthreads();

    for (int idx = tid; idx < 24 * HD; idx += 256) {
        int j = idx >> 6, oo = idx & 63;
        int r = j / 3, k = j % 3;
        float s = 0.f;
#pragma unroll
        for (int bb = 0; bb < N_BASES; bb++)
            s += w_comp[r * N_BASES + bb] * sA[(bb * 3 + k) * HD + oo];
        sG[j * HD + oo] = s;
    }
    if (tid < 3 * HD) {
        int k = tid >> 6, oo = tid & 63;
        float s = 0.f;
        for (int i = 0; i < HD; i++) {
            float w = (k == 0) ? W_in[i] : (k == 1) ? W_in[HD + i] : b_in[i];
            s += w * loop_w[i * HD + oo];
        }
        if (k == 2) s += h_bias[oo];
        sG[(24 + k) * HD + oo] = s;
    }
    __syncthreads();

    // ---- D-table projection (same as measured r16 kernel) ----
    const int v = blockIdx.x * 256 + tid;
    float part = 0.f;

    if (v < N_NODES) {
        vfloat4 Fr[16];
#pragma unroll
        for (int k = 0; k < 16; k++) Fr[k] = __builtin_nontemporal_load(&fcW4[v * 16 + k]);

        float s[27];
#pragma unroll
        for (int j = 0; j < 27; j++) {
            float acc = 0.f;
#pragma unroll
            for (int k = 0; k < 16; k++) {
                // uniform LDS addresses -> broadcast reads, conflict-free
                float gx = sG[j * HD + 4 * k + 0];
                float gy = sG[j * HD + 4 * k + 1];
                float gz = sG[j * HD + 4 * k + 2];
                float gw = sG[j * HD + 4 * k + 3];
                acc += Fr[k].x * gx + Fr[k].y * gy + Fr[k].z * gz + Fr[k].w * gw;
            }
            s[j] = acc;
        }

        // pack rels (2j, 2j+1) into one 16B store; node v occupies D16[v*4 .. v*4+4)
#pragma unroll
        for (int j = 0; j < 4; j++) {
            half8v pk;
            pk[0] = (_Float16)s[6 * j + 0];
            pk[1] = (_Float16)s[6 * j + 1];
            pk[2] = (_Float16)s[6 * j + 2];
            pk[3] = (_Float16)0.f;
            pk[4] = (_Float16)s[6 * j + 3];
            pk[5] = (_Float16)s[6 * j + 4];
            pk[6] = (_Float16)s[6 * j + 5];
            pk[7] = (_Float16)0.f;
            D16[v * 4 + j] = pk;
        }

        float2 f = feat[v];
        part = s[24] * f.x + s[25] * f.y + s[26];
    }

    // shuffle block reduce (wave64), single barrier
    for (int off = 32; off; off >>= 1) part += __shfl_down(part, off);
    __shared__ float wred[4];
    if ((threadIdx.x & 63) == 0) wred[threadIdx.x >> 6] = part;
    __syncthreads();
    if (threadIdx.x == 0) partD[blockIdx.x] = wred[0] + wred[1] + wred[2] + wred[3];
}

// ---------------------------------------------------------------------------
// Pure gather over edges: 4 quads per thread (measured best; MSHR-capped).
// Last-done block (ticket, 391 atomics total) reduces all partials with
// agent-scope loads, applies bias+sigmoid, writes out — final launch removed.
__global__ __launch_bounds__(256) void edge_gather_kernel(
        const vint4* __restrict__ src4,
        const vint4* __restrict__ dst4,
        const vint4* __restrict__ et4,
        const float2* __restrict__ feat,
        const half4v* __restrict__ D8,  // index v*8 + r
        float* __restrict__ part,       // full partials array [NB_D + NB_E]
        int* __restrict__ ticket,
        const float* __restrict__ fc_b,
        float* __restrict__ out) {
    const int t = blockIdx.x * 256 + threadIdx.x;
    const int qA = t;                    // < 100096 <= NQUAD: valid
    const int qB = t + NTHR_E;           // < 200192: valid
    const int qC = t + 2 * NTHR_E;       // < 300288: valid
    const int qDraw = t + 3 * NTHR_E;    // may exceed 400000
    const int qD = (qDraw < NQUAD) ? qDraw : (NQUAD - 1);
    const float wD = (qDraw < NQUAD) ? 1.f : 0.f;

    vint4 uA = __builtin_nontemporal_load(&src4[qA]);
    vint4 vA = __builtin_nontemporal_load(&dst4[qA]);
    vint4 rA = __builtin_nontemporal_load(&et4[qA]);
    vint4 uB = __builtin_nontemporal_load(&src4[qB]);
    vint4 vB = __builtin_nontemporal_load(&dst4[qB]);
    vint4 rB = __builtin_nontemporal_load(&et4[qB]);
    vint4 uC = __builtin_nontemporal_load(&src4[qC]);
    vint4 vC = __builtin_nontemporal_load(&dst4[qC]);
    vint4 rC = __builtin_nontemporal_load(&et4[qC]);
    vint4 uD = __builtin_nontemporal_load(&src4[qD]);
    vint4 vD = __builtin_nontemporal_load(&dst4[qD]);
    vint4 rD = __builtin_nontemporal_load(&et4[qD]);

    float2 fA0 = feat[uA.x], fA1 = feat[uA.y], fA2 = feat[uA.z], fA3 = feat[uA.w];
    float2 fB0 = feat[uB.x], fB1 = feat[uB.y], fB2 = feat[uB.z], fB3 = feat[uB.w];
    float2 fC0 = feat[uC.x], fC1 = feat[uC.y], fC2 = feat[uC.z], fC3 = feat[uC.w];
    float2 fD0 = feat[uD.x], fD1 = feat[uD.y], fD2 = feat[uD.z], fD3 = feat[uD.w];

    half4v hA0 = D8[vA.x * 8 + rA.x], hA1 = D8[vA.y * 8 + rA.y];
    half4v hA2 = D8[vA.z * 8 + rA.z], hA3 = D8[vA.w * 8 + rA.w];
    half4v hB0 = D8[vB.x * 8 + rB.x], hB1 = D8[vB.y * 8 + rB.y];
    half4v hB2 = D8[vB.z * 8 + rB.z], hB3 = D8[vB.w * 8 + rB.w];
    half4v hC0 = D8[vC.x * 8 + rC.x], hC1 = D8[vC.y * 8 + rC.y];
    half4v hC2 = D8[vC.z * 8 + rC.z], hC3 = D8[vC.w * 8 + rC.w];
    half4v hD0 = D8[vD.x * 8 + rD.x], hD1 = D8[vD.y * 8 + rD.y];
    half4v hD2 = D8[vD.z * 8 + rD.z], hD3 = D8[vD.w * 8 + rD.w];

    float sA = fA0.x * (float)hA0.x + fA0.y * (float)hA0.y + (float)hA0.z;
    sA      += fA1.x * (float)hA1.x + fA1.y * (float)hA1.y + (float)hA1.z;
    sA      += fA2.x * (float)hA2.x + fA2.y * (float)hA2.y + (float)hA2.z;
    sA      += fA3.x * (float)hA3.x + fA3.y * (float)hA3.y + (float)hA3.z;
    float sB = fB0.x * (float)hB0.x + fB0.y * (float)hB0.y + (float)hB0.z;
    sB      += fB1.x * (float)hB1.x + fB1.y * (float)hB1.y + (float)hB1.z;
    sB      += fB2.x * (float)hB2.x + fB2.y * (float)hB2.y + (float)hB2.z;
    sB      += fB3.x * (float)hB3.x + fB3.y * (float)hB3.y + (float)hB3.z;
    float sC = fC0.x * (float)hC0.x + fC0.y * (float)hC0.y + (float)hC0.z;
    sC      += fC1.x * (float)hC1.x + fC1.y * (float)hC1.y + (float)hC1.z;
    sC      += fC2.x * (float)hC2.x + fC2.y * (float)hC2.y + (float)hC2.z;
    sC      += fC3.x * (float)hC3.x + fC3.y * (float)hC3.y + (float)hC3.z;
    float sD = fD0.x * (float)hD0.x + fD0.y * (float)hD0.y + (float)hD0.z;
    sD      += fD1.x * (float)hD1.x + fD1.y * (float)hD1.y + (float)hD1.z;
    sD      += fD2.x * (float)hD2.x + fD2.y * (float)hD2.y + (float)hD2.z;
    sD      += fD3.x * (float)hD3.x + fD3.y * (float)hD3.y + (float)hD3.z;
    float s = (sA + sB) + (sC + wD * sD);

    // shuffle block reduce (wave64), single barrier
    for (int off = 32; off; off >>= 1) s += __shfl_down(s, off);
    __shared__ float wred[4];
    __shared__ int lastFlag;
    if ((threadIdx.x & 63) == 0) wred[threadIdx.x >> 6] = s;
    __syncthreads();
    if (threadIdx.x == 0) {
        part[NB_D + blockIdx.x] = wred[0] + wred[1] + wred[2] + wred[3];
        __threadfence();                                   // release partial
        int tk = atomicAdd(ticket, 1);                     // device-scope
        lastFlag = (tk == NB_E - 1);
    }
    __syncthreads();

    if (lastFlag) {
        __threadfence();                                   // acquire
        float fs = 0.f;
        for (int i = threadIdx.x; i < NB_D + NB_E; i += 256) {
            // agent-scope load: served at the coherent point — partials were
            // written by blocks on other XCDs (per-XCD L2 not coherent).
            fs += __hip_atomic_load(&part[i], __ATOMIC_RELAXED, __HIP_MEMORY_SCOPE_AGENT);
        }
        for (int off = 32; off; off >>= 1) fs += __shfl_down(fs, off);
        if ((threadIdx.x & 63) == 0) wred[threadIdx.x >> 6] = fs;
        __syncthreads();
        if (threadIdx.x == 0) {
            float x = wred[0] + wred[1] + wred[2] + wred[3] + fc_b[0];
            out[0] = 1.0f / (1.0f + expf(-x));
        }
    }
}

// ---------------------------------------------------------------------------
extern "C" void kernel_launch(void* const* d_in, const int* in_sizes, int n_in,
                              void* d_out, int out_size, void* d_ws, size_t ws_size,
                              hipStream_t stream) {
    const float* features = (const float*)d_in[0];
    const int*   src      = (const int*)d_in[1];
    const int*   dst      = (const int*)d_in[2];
    const int*   etype    = (const int*)d_in[3];
    const float* W_in     = (const float*)d_in[4];
    const float* b_in     = (const float*)d_in[5];
    const float* w_comp   = (const float*)d_in[6];
    const float* bases    = (const float*)d_in[7];
    const float* loop_w   = (const float*)d_in[8];
    const float* h_bias   = (const float*)d_in[9];
    const float* fc_W     = (const float*)d_in[10];
    const float* fc_b     = (const float*)d_in[11];

    float* ws     = (float*)d_ws;
    float* part   = ws + PART_OFF;
    int*   ticket = (int*)(ws + TICKET_OFF);
    half8v* D16   = (half8v*)(ws + D_OFF);
    half4v* D8    = (half4v*)(ws + D_OFF);
    float* out    = (float*)d_out;

    d_table_kernel<<<NB_D, 256, 0, stream>>>(
        W_in, b_in, w_comp, bases, loop_w, h_bias,
        (const vfloat4*)fc_W, (const float2*)features, D16, part, ticket);
    edge_gather_kernel<<<NB_E, 256, 0, stream>>>(
        (const vint4*)src, (const vint4*)dst, (const vint4*)etype,
        (const float2*)features, D8, part, ticket, fc_b, out);
}

// Round 20
// 138.452 us; speedup vs baseline: 1.0668x; 1.0668x over previous
//
#include <hip/hip_runtime.h>
#include <math.h>

#define N_NODES 50000
#define N_EDGES 1600000
#define N_RELS 8
#define N_BASES 4
#define HD 64

#define NB_D 196                 // ceil(50000/256) blocks in d_table_kernel
#define NB_E 391                 // edge kernel: 391*256 threads * 4 quads = 400384 >= 400000
#define NTHR_E (NB_E * 256)      // 100096
#define NQUAD (N_EDGES / 4)      // 400000

typedef int      vint4   __attribute__((ext_vector_type(4)));
typedef float    vfloat4 __attribute__((ext_vector_type(4)));
typedef _Float16 half4v  __attribute__((ext_vector_type(4)));   // 8B: one (v,r) D entry
typedef _Float16 half8v  __attribute__((ext_vector_type(8)));   // 16B: two entries (store side)

// ws layout (floats):
//   partials    at PART_OFF   [0..NB_D+NB_E)
//   D           at D_OFF      v-major fp16: half4v index = v*8 + r
//                             (d0,d1,d2,0) per (v,r) -> 8B, 64B per node, 3.2 MB total
#define PART_OFF   0
#define D_OFF      4096

// ---------------------------------------------------------------------------
// Fused: per-block G build (in LDS) + D-table projection.
// Every block redundantly computes G[27][64] from the tiny weight tensors
// (bases et al. are L2-resident after block 0) -> no separate prep launch,
// and the hot G reads become LDS broadcasts instead of L2 scalar loads.
__global__ __launch_bounds__(256) void d_table_kernel(
        const float* __restrict__ W_in,
        const float* __restrict__ b_in,
        const float* __restrict__ w_comp,
        const float* __restrict__ bases,
        const float* __restrict__ loop_w,
        const float* __restrict__ h_bias,
        const vfloat4* __restrict__ fcW4,
        const float2* __restrict__ feat,
        half8v* __restrict__ D16,        // index v*4 + j  (rel pair j)
        float* __restrict__ partD) {
    __shared__ float sA[N_BASES * 3 * HD];   // A[b][k][o]
    __shared__ float sG[27 * HD];            // G[j][o]
    const int tid = threadIdx.x;

    // ---- G build (identical math to the old prep_kernel, LDS-resident) ----
    {
        const int o = tid & 63;
        const int b = tid >> 6;              // 0..3
        float s0 = 0.f, s1 = 0.f, sb = 0.f;
        for (int i = 0; i < HD; i++) {
            float bv = bases[b * HD * HD + i * HD + o];
            s0 += W_in[i]      * bv;
            s1 += W_in[HD + i] * bv;
            sb += b_in[i]      * bv;
        }
        sA[(b * 3 + 0) * HD + o] = s0;
        sA[(b * 3 + 1) * HD + o] = s1;
        sA[(b * 3 + 2) * HD + o] = sb;
    }
    __syncthreads();

    for (int idx = tid; idx < 24 * HD; idx += 256) {
        int j = idx >> 6, oo = idx & 63;
        int r = j / 3, k = j % 3;
        float s = 0.f;
#pragma unroll
        for (int bb = 0; bb < N_BASES; bb++)
            s += w_comp[r * N_BASES + bb] * sA[(bb * 3 + k) * HD + oo];
        sG[j * HD + oo] = s;
    }
    if (tid < 3 * HD) {
        int k = tid >> 6, oo = tid & 63;
        float s = 0.f;
        for (int i = 0; i < HD; i++) {
            float w = (k == 0) ? W_in[i] : (k == 1) ? W_in[HD + i] : b_in[i];
            s += w * loop_w[i * HD + oo];
        }
        if (k == 2) s += h_bias[oo];
        sG[(24 + k) * HD + oo] = s;
    }
    __syncthreads();

    // ---- D-table projection ----
    const int v = blockIdx.x * 256 + tid;
    float part = 0.f;

    if (v < N_NODES) {
        vfloat4 Fr[16];
#pragma unroll
        for (int k = 0; k < 16; k++) Fr[k] = __builtin_nontemporal_load(&fcW4[v * 16 + k]);

        float s[27];
#pragma unroll
        for (int j = 0; j < 27; j++) {
            float acc = 0.f;
#pragma unroll
            for (int k = 0; k < 16; k++) {
                // uniform LDS addresses -> broadcast reads, conflict-free
                float gx = sG[j * HD + 4 * k + 0];
                float gy = sG[j * HD + 4 * k + 1];
                float gz = sG[j * HD + 4 * k + 2];
                float gw = sG[j * HD + 4 * k + 3];
                acc += Fr[k].x * gx + Fr[k].y * gy + Fr[k].z * gz + Fr[k].w * gw;
            }
            s[j] = acc;
        }

        // pack rels (2j, 2j+1) into one 16B store; node v occupies D16[v*4 .. v*4+4)
#pragma unroll
        for (int j = 0; j < 4; j++) {
            half8v pk;
            pk[0] = (_Float16)s[6 * j + 0];
            pk[1] = (_Float16)s[6 * j + 1];
            pk[2] = (_Float16)s[6 * j + 2];
            pk[3] = (_Float16)0.f;
            pk[4] = (_Float16)s[6 * j + 3];
            pk[5] = (_Float16)s[6 * j + 4];
            pk[6] = (_Float16)s[6 * j + 5];
            pk[7] = (_Float16)0.f;
            D16[v * 4 + j] = pk;
        }

        float2 f = feat[v];
        part = s[24] * f.x + s[25] * f.y + s[26];
    }

    // shuffle block reduce (wave64), single barrier
    for (int off = 32; off; off >>= 1) part += __shfl_down(part, off);
    __shared__ float wred[4];
    if ((threadIdx.x & 63) == 0) wred[threadIdx.x >> 6] = part;
    __syncthreads();
    if (threadIdx.x == 0) partD[blockIdx.x] = wred[0] + wred[1] + wred[2] + wred[3];
}

// ---------------------------------------------------------------------------
// Pure gather over edges: 4 quads per thread, straight-line (branch-free
// clamped tail on quad D only) -> 44 loads in flight per lane. fp16 D gathers
// (8B) from a 3.2 MB L2-resident table. One partial per block.
// (Measured: 2-quad ~43 µs, 4-quad ~2 µs faster total -> MSHR-capped.)
__global__ __launch_bounds__(256) void edge_gather_kernel(
        const vint4* __restrict__ src4,
        const vint4* __restrict__ dst4,
        const vint4* __restrict__ et4,
        const float2* __restrict__ feat,
        const half4v* __restrict__ D8,  // index v*8 + r
        float* __restrict__ partE) {
    const int t = blockIdx.x * 256 + threadIdx.x;
    const int qA = t;                    // < 100096 <= NQUAD: valid
    const int qB = t + NTHR_E;           // < 200192: valid
    const int qC = t + 2 * NTHR_E;       // < 300288: valid
    const int qDraw = t + 3 * NTHR_E;    // may exceed 400000
    const int qD = (qDraw < NQUAD) ? qDraw : (NQUAD - 1);
    const float wD = (qDraw < NQUAD) ? 1.f : 0.f;

    vint4 uA = __builtin_nontemporal_load(&src4[qA]);
    vint4 vA = __builtin_nontemporal_load(&dst4[qA]);
    vint4 rA = __builtin_nontemporal_load(&et4[qA]);
    vint4 uB = __builtin_nontemporal_load(&src4[qB]);
    vint4 vB = __builtin_nontemporal_load(&dst4[qB]);
    vint4 rB = __builtin_nontemporal_load(&et4[qB]);
    vint4 uC = __builtin_nontemporal_load(&src4[qC]);
    vint4 vC = __builtin_nontemporal_load(&dst4[qC]);
    vint4 rC = __builtin_nontemporal_load(&et4[qC]);
    vint4 uD = __builtin_nontemporal_load(&src4[qD]);
    vint4 vD = __builtin_nontemporal_load(&dst4[qD]);
    vint4 rD = __builtin_nontemporal_load(&et4[qD]);

    float2 fA0 = feat[uA.x], fA1 = feat[uA.y], fA2 = feat[uA.z], fA3 = feat[uA.w];
    float2 fB0 = feat[uB.x], fB1 = feat[uB.y], fB2 = feat[uB.z], fB3 = feat[uB.w];
    float2 fC0 = feat[uC.x], fC1 = feat[uC.y], fC2 = feat[uC.z], fC3 = feat[uC.w];
    float2 fD0 = feat[uD.x], fD1 = feat[uD.y], fD2 = feat[uD.z], fD3 = feat[uD.w];

    half4v hA0 = D8[vA.x * 8 + rA.x], hA1 = D8[vA.y * 8 + rA.y];
    half4v hA2 = D8[vA.z * 8 + rA.z], hA3 = D8[vA.w * 8 + rA.w];
    half4v hB0 = D8[vB.x * 8 + rB.x], hB1 = D8[vB.y * 8 + rB.y];
    half4v hB2 = D8[vB.z * 8 + rB.z], hB3 = D8[vB.w * 8 + rB.w];
    half4v hC0 = D8[vC.x * 8 + rC.x], hC1 = D8[vC.y * 8 + rC.y];
    half4v hC2 = D8[vC.z * 8 + rC.z], hC3 = D8[vC.w * 8 + rC.w];
    half4v hD0 = D8[vD.x * 8 + rD.x], hD1 = D8[vD.y * 8 + rD.y];
    half4v hD2 = D8[vD.z * 8 + rD.z], hD3 = D8[vD.w * 8 + rD.w];

    float sA = fA0.x * (float)hA0.x + fA0.y * (float)hA0.y + (float)hA0.z;
    sA      += fA1.x * (float)hA1.x + fA1.y * (float)hA1.y + (float)hA1.z;
    sA      += fA2.x * (float)hA2.x + fA2.y * (float)hA2.y + (float)hA2.z;
    sA      += fA3.x * (float)hA3.x + fA3.y * (float)hA3.y + (float)hA3.z;
    float sB = fB0.x * (float)hB0.x + fB0.y * (float)hB0.y + (float)hB0.z;
    sB      += fB1.x * (float)hB1.x + fB1.y * (float)hB1.y + (float)hB1.z;
    sB      += fB2.x * (float)hB2.x + fB2.y * (float)hB2.y + (float)hB2.z;
    sB      += fB3.x * (float)hB3.x + fB3.y * (float)hB3.y + (float)hB3.z;
    float sC = fC0.x * (float)hC0.x + fC0.y * (float)hC0.y + (float)hC0.z;
    sC      += fC1.x * (float)hC1.x + fC1.y * (float)hC1.y + (float)hC1.z;
    sC      += fC2.x * (float)hC2.x + fC2.y * (float)hC2.y + (float)hC2.z;
    sC      += fC3.x * (float)hC3.x + fC3.y * (float)hC3.y + (float)hC3.z;
    float sD = fD0.x * (float)hD0.x + fD0.y * (float)hD0.y + (float)hD0.z;
    sD      += fD1.x * (float)hD1.x + fD1.y * (float)hD1.y + (float)hD1.z;
    sD      += fD2.x * (float)hD2.x + fD2.y * (float)hD2.y + (float)hD2.z;
    sD      += fD3.x * (float)hD3.x + fD3.y * (float)hD3.y + (float)hD3.z;
    float s = (sA + sB) + (sC + wD * sD);

    // shuffle block reduce (wave64), single barrier
    for (int off = 32; off; off >>= 1) s += __shfl_down(s, off);
    __shared__ float wred[4];
    if ((threadIdx.x & 63) == 0) wred[threadIdx.x >> 6] = s;
    __syncthreads();
    if (threadIdx.x == 0) partE[blockIdx.x] = wred[0] + wred[1] + wred[2] + wred[3];
}

// ---------------------------------------------------------------------------
// Separate 1-block final reduce: inter-dispatch ordering guarantees
// visibility of all partials — no fences/atomics needed.
// (Measured r19: folding this into the edge kernel via ticket REGRESSED
//  140.6 -> 147.7 µs — per-block device fences + serialized agent-scope
//  tail reduce cost more than one tiny launch.)
__global__ void final_kernel(const float* __restrict__ part,
                             const float* __restrict__ fc_b,
                             float* __restrict__ out) {
    float s = 0.f;
    for (int i = threadIdx.x; i < NB_D + NB_E; i += 256) s += part[i];
    for (int off = 32; off; off >>= 1) s += __shfl_down(s, off);
    __shared__ float wred[4];
    if ((threadIdx.x & 63) == 0) wred[threadIdx.x >> 6] = s;
    __syncthreads();
    if (threadIdx.x == 0) {
        float x = wred[0] + wred[1] + wred[2] + wred[3] + fc_b[0];
        out[0] = 1.0f / (1.0f + expf(-x));
    }
}

// ---------------------------------------------------------------------------
extern "C" void kernel_launch(void* const* d_in, const int* in_sizes, int n_in,
                              void* d_out, int out_size, void* d_ws, size_t ws_size,
                              hipStream_t stream) {
    const float* features = (const float*)d_in[0];
    const int*   src      = (const int*)d_in[1];
    const int*   dst      = (const int*)d_in[2];
    const int*   etype    = (const int*)d_in[3];
    const float* W_in     = (const float*)d_in[4];
    const float* b_in     = (const float*)d_in[5];
    const float* w_comp   = (const float*)d_in[6];
    const float* bases    = (const float*)d_in[7];
    const float* loop_w   = (const float*)d_in[8];
    const float* h_bias   = (const float*)d_in[9];
    const float* fc_W     = (const float*)d_in[10];
    const float* fc_b     = (const float*)d_in[11];

    float* ws   = (float*)d_ws;
    float* part = ws + PART_OFF;
    half8v* D16 = (half8v*)(ws + D_OFF);
    half4v* D8  = (half4v*)(ws + D_OFF);
    float* out  = (float*)d_out;

    d_table_kernel<<<NB_D, 256, 0, stream>>>(
        W_in, b_in, w_comp, bases, loop_w, h_bias,
        (const vfloat4*)fc_W, (const float2*)features, D16, part);
    edge_gather_kernel<<<NB_E, 256, 0, stream>>>(
        (const vint4*)src, (const vint4*)dst, (const vint4*)etype,
        (const float2*)features, D8, part + NB_D);
    final_kernel<<<1, 256, 0, stream>>>(part, fc_b, out);
}